// Round 9
// baseline (64.566 us; speedup 1.0000x reference)
//
#include <hip/hip_runtime.h>
#include <hip/hip_bf16.h>

typedef __attribute__((ext_vector_type(8))) short short8;
typedef __attribute__((ext_vector_type(4))) float f32x4;
typedef __attribute__((ext_vector_type(16))) float f32x16;

#define DEVI __device__ __forceinline__

DEVI unsigned short f2bf(float f) {
  union { float f; unsigned int u; } v; v.f = f;
  unsigned int r = v.u + 0x7fffu + ((v.u >> 16) & 1u);
  return (unsigned short)(r >> 16);
}

DEVI unsigned int cvt2(float lo, float hi) {  // v_cvt_pk_bf16_f32 (RNE)
  unsigned int r;
  asm("v_cvt_pk_bf16_f32 %0, %1, %2" : "=v"(r) : "v"(lo), "v"(hi));
  return r;
}

// direct global->LDS, 16B per lane. dest = wave-uniform base + lane*16 (linear).
#define GLDS16(gp, lp)                                                         \
  __builtin_amdgcn_global_load_lds(                                            \
      (const __attribute__((address_space(1))) unsigned int*)(uintptr_t)(gp),  \
      (__attribute__((address_space(3))) unsigned int*)(uintptr_t)(lp), 16, 0, 0)

// problem sizes
#define SB 4
#define SS 2048
#define SD 256
#define SH 8
#define SDH 32
#define SM 8192  // B*S

// softmax scale folded into Q:  (1/sqrt(S)) * log2(e)
#define QSCALE 0.0318793654f

// workspace layout: bf16 Q/K/V^T, then f32 attention partials
#define Q_OFF   0                 // ushort idx: [BH][S][dh] (Q pre-scaled)
#define K_OFF   (SM * SD)         // [BH][S][dh]
#define VT_OFF  (2 * SM * SD)     // [BH][dh][S]
#define OPF     3145728           // float idx from ws base: [2][M][D] O partials
#define LPF     (OPF + 2 * SM * SD)  // float idx: [2][BH][S] L partials

// ---------------- kernel 1: fused convert + QKV projection, 128x128 tile ----
// (byte-identical to R7)
__global__ __launch_bounds__(256) void qkv_k(
    const float* __restrict__ X, const float* __restrict__ Wq,
    const float* __restrict__ Wk, const float* __restrict__ Wv,
    unsigned short* __restrict__ ws) {
  __shared__ __align__(16) unsigned short Atile[128][72];
  __shared__ __align__(16) unsigned short Btile[128][72];
  int tid = threadIdx.x, w = tid >> 6, lane = tid & 63, g = lane >> 4, r = lane & 15;
  int m0 = blockIdx.x * 128, n0 = blockIdx.y * 128;
  int z = n0 >> 8, nbase = n0 & 255;
  const float* Wz = (z == 0) ? Wq : (z == 1) ? Wk : Wv;
  int wr = (w >> 1) * 64, wc = (w & 1) * 64;
  f32x4 acc[4][4] = {};
  int srow = tid >> 3, scol = (tid & 7) * 8;
  float4 a0[4], a1[4], b0[4], b1[4];
#pragma unroll
  for (int p = 0; p < 4; ++p) {
    const float* xa = X + (m0 + srow + p * 32) * SD + scol;
    const float* xb = Wz + (nbase + srow + p * 32) * SD + scol;
    a0[p] = *reinterpret_cast<const float4*>(xa);
    a1[p] = *reinterpret_cast<const float4*>(xa + 4);
    b0[p] = *reinterpret_cast<const float4*>(xb);
    b1[p] = *reinterpret_cast<const float4*>(xb + 4);
  }
  for (int k0 = 0; k0 < SD; k0 += 64) {
    __syncthreads();
#pragma unroll
    for (int p = 0; p < 4; ++p) {
      uint4 ua = { cvt2(a0[p].x, a0[p].y), cvt2(a0[p].z, a0[p].w),
                   cvt2(a1[p].x, a1[p].y), cvt2(a1[p].z, a1[p].w) };
      uint4 ub = { cvt2(b0[p].x, b0[p].y), cvt2(b0[p].z, b0[p].w),
                   cvt2(b1[p].x, b1[p].y), cvt2(b1[p].z, b1[p].w) };
      *reinterpret_cast<uint4*>(&Atile[srow + p * 32][scol]) = ua;
      *reinterpret_cast<uint4*>(&Btile[srow + p * 32][scol]) = ub;
    }
    __syncthreads();
    if (k0 + 64 < SD) {
#pragma unroll
      for (int p = 0; p < 4; ++p) {
        const float* xa = X + (m0 + srow + p * 32) * SD + k0 + 64 + scol;
        const float* xb = Wz + (nbase + srow + p * 32) * SD + k0 + 64 + scol;
        a0[p] = *reinterpret_cast<const float4*>(xa);
        a1[p] = *reinterpret_cast<const float4*>(xa + 4);
        b0[p] = *reinterpret_cast<const float4*>(xb);
        b1[p] = *reinterpret_cast<const float4*>(xb + 4);
      }
    }
#pragma unroll
    for (int ks = 0; ks < 2; ++ks) {
      short8 af[4], bf[4];
#pragma unroll
      for (int i = 0; i < 4; ++i)
        af[i] = *reinterpret_cast<const short8*>(&Atile[wr + i * 16 + r][ks * 32 + g * 8]);
#pragma unroll
      for (int j = 0; j < 4; ++j)
        bf[j] = *reinterpret_cast<const short8*>(&Btile[wc + j * 16 + r][ks * 32 + g * 8]);
#pragma unroll
      for (int i = 0; i < 4; ++i)
#pragma unroll
        for (int j = 0; j < 4; ++j)
          acc[i][j] = __builtin_amdgcn_mfma_f32_16x16x32_bf16(af[i], bf[j], acc[i][j], 0, 0, 0);
    }
  }
  int b_ = m0 >> 11, sbase = m0 & 2047;
  float qs = (z == 0) ? QSCALE : 1.0f;
  unsigned short* Vt = &Btile[0][0];  // reused as [64][136]
#pragma unroll
  for (int p = 0; p < 2; ++p) {       // n-half pass: cols p*64 .. p*64+63
    __syncthreads();
    if ((w & 1) == p) {
      if (z < 2) {
#pragma unroll
        for (int i = 0; i < 4; ++i)
#pragma unroll
          for (int j = 0; j < 4; ++j)
#pragma unroll
            for (int jj = 0; jj < 4; ++jj)
              Atile[wr + i * 16 + g * 4 + jj][j * 16 + r] = f2bf(acc[i][j][jj] * qs);
      } else {
#pragma unroll
        for (int i = 0; i < 4; ++i)
#pragma unroll
          for (int j = 0; j < 4; ++j) {
            unsigned short o4[4];
#pragma unroll
            for (int jj = 0; jj < 4; ++jj) o4[jj] = f2bf(acc[i][j][jj]);
            *reinterpret_cast<uint2*>(&Vt[(j * 16 + r) * 136 + wr + i * 16 + g * 4]) =
                *reinterpret_cast<const uint2*>(o4);
          }
      }
    }
    __syncthreads();
    if (z < 2) {
      unsigned short* out = ws + (z == 0 ? Q_OFF : K_OFF);
      int h0 = (nbase + p * 64) >> 5;
#pragma unroll
      for (int it = 0; it < 4; ++it) {
        int c = it * 256 + tid;                  // 1024 chunks of 16B
        int m = c >> 3, cr = c & 7, hl = cr >> 2, ch = cr & 3;
        short8 val = *reinterpret_cast<const short8*>(&Atile[m][hl * 32 + ch * 8]);
        int h = h0 + hl;
        *reinterpret_cast<short8*>(
            out + (((b_ << 3) + h) * SS + sbase + m) * SDH + ch * 8) = val;
      }
    } else {
      unsigned short* out = ws + VT_OFF;
      int nb = nbase + p * 64;
#pragma unroll
      for (int it = 0; it < 4; ++it) {
        int c = it * 256 + tid;                  // 1024 chunks of 16B
        int nl = c >> 4, ch = c & 15;
        short8 val = *reinterpret_cast<const short8*>(&Vt[nl * 136 + ch * 8]);
        int col = nb + nl, h = col >> 5, d = col & 31;
        *reinterpret_cast<short8*>(
            out + ((((b_ << 3) + h) << 5) + d) * SS + sbase + ch * 8) = val;
      }
    }
  }
}

// ---------------- kernel 2: flash attention, occupancy-doubled ----------------
// grid 1024 = 32 bh x 16 qb x 2 kvh (XCD-swizzled), 512 thr = 8 waves.
// Within block: waves 0-3 kv [base,base+512), waves 4-7 [base+512,base+1024);
// each wave 32 q x 512 kv. TKV=64, LDS 32 KB (dbuf) -> 4 blocks/CU resident
// (vs 2 before): doubles waves/SIMD to hide the 30% no-issue stall seen in R5.
// Fixed-M softmax -> partial (O,L) add linearly: in-block 2-way combine via
// LDS, then f32 partials per kvh to workspace; final_k folds the kvh combine.
__global__ __launch_bounds__(512, 6) void attn_k(const unsigned short* __restrict__ ws_c,
                                                 unsigned short* __restrict__ ws) {
  __shared__ __align__(16) unsigned char smem[32768];
  int tid = threadIdx.x, w = tid >> 6, lane = tid & 63;
  int wg = w >> 2, wl = w & 3, gtid = tid & 255;
  int n32 = lane & 31, hi = lane >> 5;
  // XCD-aware swizzle (1024 % 8 == 0 -> bijective): 4 heads per XCD
  int wgid = ((blockIdx.x & 7) << 7) + (blockIdx.x >> 3);
  int bh = wgid >> 5, qb = (wgid >> 1) & 15, kvh = wgid & 1;
  int q0 = qb * 128 + wl * 32;
  const unsigned short* Qh = ws_c + Q_OFF + bh * (SS * SDH);
  const unsigned short* Kg = ws_c + K_OFF + (bh * SS + kvh * 1024 + wg * 512) * SDH;
  const unsigned short* Vg = ws_c + VT_OFF + bh * (SDH * SS) + kvh * 1024 + wg * 512;
  // Q B-frags: lane holds col q=n32, k = 8*hi + j (dh halves)
  short8 qB0 = *reinterpret_cast<const short8*>(Qh + (q0 + n32) * SDH + 8 * hi);
  short8 qB1 = *reinterpret_cast<const short8*>(Qh + (q0 + n32) * SDH + 16 + 8 * hi);
  // staging sources (inverse-swizzled so linear LDS dest ends up swizzled)
  int kr = gtid >> 2, kcg = (gtid & 3) ^ ((kr >> 1) & 3);
  const unsigned short* gK = Kg + kr * SDH + kcg * 8;
  int vr = gtid >> 3, vcg = (gtid & 7) ^ (vr & 7);
  const unsigned short* gV = Vg + vr * SS + vcg * 8;
  int wv = gtid >> 6;  // wave index within group (wave-uniform)
  auto issue = [&](int buf, int tt) {
    char* kd = (char*)smem + wg * 8192 + buf * 4096 + wv * 1024;
    char* vd = (char*)smem + 16384 + wg * 8192 + buf * 4096 + wv * 1024;
    GLDS16(gK + tt * 2048, kd);   // K tile: 64 rows x 32 dh (4 KB)
    GLDS16(gV + tt * 64, vd);     // V tile: 32 d x 64 kv (4 KB)
  };
  issue(0, 0);
  f32x16 O = {}, Lf = {};
  union { unsigned int u[4]; short8 sv; } ONES;
  ONES.u[0] = 0x3F803F80u; ONES.u[1] = 0x3F803F80u;
  ONES.u[2] = 0x3F803F80u; ONES.u[3] = 0x3F803F80u;
  // read-side swizzle constants
  int rb = (n32 >> 1) & 3;
  int koff0 = (hi ^ rb) * 8;
  int koff1 = ((2 + hi) ^ rb) * 8;
  int vb7 = n32 & 7;
  for (int t = 0; t < 8; ++t) {
    const unsigned short* Kt = (const unsigned short*)(smem + wg * 8192 + (t & 1) * 4096);
    const unsigned short* Vt = (const unsigned short*)(smem + 16384 + wg * 8192 + (t & 1) * 4096);
    if (t < 7) {
      issue((t + 1) & 1, t + 1);
      asm volatile("s_waitcnt vmcnt(2)" ::: "memory");  // tile t landed; t+1 in flight
    } else {
      asm volatile("s_waitcnt vmcnt(0)" ::: "memory");
    }
    __builtin_amdgcn_s_barrier();
#pragma unroll
    for (int s = 0; s < 2; ++s) {
      const unsigned short* krow = Kt + (s * 32 + n32) * 32;
      short8 ka = *reinterpret_cast<const short8*>(krow + koff0);
      short8 kb = *reinterpret_cast<const short8*>(krow + koff1);
      f32x16 aC = {};
      __builtin_amdgcn_s_setprio(1);
      aC = __builtin_amdgcn_mfma_f32_32x32x16_bf16(ka, qB0, aC, 0, 0, 0);
      aC = __builtin_amdgcn_mfma_f32_32x32x16_bf16(kb, qB1, aC, 0, 0, 0);
      __builtin_amdgcn_s_setprio(0);
#pragma unroll
      for (int i = 0; i < 16; ++i) aC[i] = __builtin_amdgcn_exp2f(aC[i]);
      unsigned int pk[8];
#pragma unroll
      for (int i = 0; i < 8; ++i) pk[i] = cvt2(aC[2 * i], aC[2 * i + 1]);
      asm("v_permlane32_swap_b32 %0, %1" : "+v"(pk[0]), "+v"(pk[2]));
      asm("v_permlane32_swap_b32 %0, %1" : "+v"(pk[1]), "+v"(pk[3]));
      asm("v_permlane32_swap_b32 %0, %1" : "+v"(pk[4]), "+v"(pk[6]));
      asm("v_permlane32_swap_b32 %0, %1" : "+v"(pk[5]), "+v"(pk[7]));
      union { unsigned int u[4]; short8 sv; } A1, A2;
      A1.u[0] = pk[0]; A1.u[1] = pk[1]; A1.u[2] = pk[2]; A1.u[3] = pk[3];
      A2.u[0] = pk[4]; A2.u[1] = pk[5]; A2.u[2] = pk[6]; A2.u[3] = pk[7];
      const unsigned short* vrow = Vt + n32 * 64;
      short8 vB0 = *reinterpret_cast<const short8*>(vrow + ((s * 4 + hi) ^ vb7) * 8);
      short8 vB1 = *reinterpret_cast<const short8*>(vrow + ((s * 4 + 2 + hi) ^ vb7) * 8);
      __builtin_amdgcn_s_setprio(1);
      O  = __builtin_amdgcn_mfma_f32_32x32x16_bf16(A1.sv, vB0, O, 0, 0, 0);
      O  = __builtin_amdgcn_mfma_f32_32x32x16_bf16(A2.sv, vB1, O, 0, 0, 0);
      Lf = __builtin_amdgcn_mfma_f32_32x32x16_bf16(A1.sv, ONES.sv, Lf, 0, 0, 0);
      Lf = __builtin_amdgcn_mfma_f32_32x32x16_bf16(A2.sv, ONES.sv, Lf, 0, 0, 0);
      __builtin_amdgcn_s_setprio(0);
    }
    __builtin_amdgcn_s_barrier();
  }
  // in-block 2-way combine (wg 0/1), then f32 partials to workspace.
  __syncthreads();
  float* OCf = reinterpret_cast<float*>(smem);   // [16][257] = 16448 B
  float* LCf = OCf + 16 * 257;                   // [4 wl][32 q] = 512 B
  int p = wl * 64 + lane;
  if (wg == 1) {
#pragma unroll
    for (int i = 0; i < 16; ++i) {
      OCf[i * 257 + p] = O[i];
      if (n32 == 0) {
        int q = (i & 3) + 8 * (i >> 2) + 4 * hi;
        LCf[wl * 32 + q] = Lf[i];
      }
    }
  }
  __syncthreads();
  if (wg == 0) {
    int b = bh >> 3, h = bh & 7;
    float* OPp = (float*)ws + OPF + (size_t)kvh * (SM * SD);
    float* LPp = (float*)ws + LPF + (size_t)kvh * (32 * SS) + bh * SS;
#pragma unroll
    for (int rr = 0; rr < 16; ++rr) {
      int q = (rr & 3) + 8 * (rr >> 2) + 4 * hi;
      float Ot = O[rr] + OCf[rr * 257 + p];
      float Lt = Lf[rr] + LCf[wl * 32 + q];
      OPp[(b * SS + q0 + q) * SD + h * SDH + n32] = Ot;
      if (n32 == 0) LPp[q0 + q] = Lt;
    }
  }
}

// ---------------- kernel 3: combine + out-proj + bias + residual + LayerNorm -
// Staging folds the cross-block kvh combine: AO = (O0+O1)/(L0+L1) -> bf16.
__global__ __launch_bounds__(256) void final_k(
    const unsigned short* __restrict__ ws_c, const float* __restrict__ X,
    const float* __restrict__ Wf, const float* __restrict__ bfv,
    const float* __restrict__ gamma, const float* __restrict__ beta,
    float* __restrict__ out) {
  __shared__ __align__(16) unsigned short Al[32][72];
  __shared__ __align__(16) unsigned short Bl[256][72];
  __shared__ float Cl[32][257];
  const float* OP0 = (const float*)ws_c + OPF;
  const float* OP1 = OP0 + (SM * SD);
  const float* LP0 = (const float*)ws_c + LPF;
  const float* LP1 = LP0 + (32 * SS);
  int tid = threadIdx.x, w = tid >> 6, lane = tid & 63, g = lane >> 4, r = lane & 15;
  int m0 = blockIdx.x * 32;
  f32x4 acc[2][4] = {};
  int arow = tid >> 3, acol = (tid & 7) * 8;
  int m = m0 + arow, b_ = m >> 11, s2 = m & 2047;
  for (int k0 = 0; k0 < SD; k0 += 64) {
    int col0 = k0 + acol;
    int h = col0 >> 5;
    float Ls = LP0[(b_ * 8 + h) * SS + s2] + LP1[(b_ * 8 + h) * SS + s2];
    float inv = 1.0f / Ls;
    const float* p0 = OP0 + (size_t)m * SD + col0;
    const float* p1 = OP1 + (size_t)m * SD + col0;
    float4 x0 = *reinterpret_cast<const float4*>(p0);
    float4 x1 = *reinterpret_cast<const float4*>(p0 + 4);
    float4 y0 = *reinterpret_cast<const float4*>(p1);
    float4 y1 = *reinterpret_cast<const float4*>(p1 + 4);
    uint4 av = { cvt2((x0.x + y0.x) * inv, (x0.y + y0.y) * inv),
                 cvt2((x0.z + y0.z) * inv, (x0.w + y0.w) * inv),
                 cvt2((x1.x + y1.x) * inv, (x1.y + y1.y) * inv),
                 cvt2((x1.z + y1.z) * inv, (x1.w + y1.w) * inv) };
    float4 w0[8], w1[8];
#pragma unroll
    for (int i = 0; i < 8; i++) {
      const float* wp = Wf + (i * 32 + arow) * SD + k0 + acol;
      w0[i] = *reinterpret_cast<const float4*>(wp);
      w1[i] = *reinterpret_cast<const float4*>(wp + 4);
    }
    __syncthreads();
    *reinterpret_cast<uint4*>(&Al[arow][acol]) = av;
#pragma unroll
    for (int i = 0; i < 8; i++) {
      uint4 ub = { cvt2(w0[i].x, w0[i].y), cvt2(w0[i].z, w0[i].w),
                   cvt2(w1[i].x, w1[i].y), cvt2(w1[i].z, w1[i].w) };
      *reinterpret_cast<uint4*>(&Bl[i * 32 + arow][acol]) = ub;
    }
    __syncthreads();
#pragma unroll
    for (int ks = 0; ks < 2; ks++) {
      short8 af0 = *reinterpret_cast<const short8*>(&Al[r][ks * 32 + g * 8]);
      short8 af1 = *reinterpret_cast<const short8*>(&Al[16 + r][ks * 32 + g * 8]);
#pragma unroll
      for (int nt = 0; nt < 4; nt++) {
        short8 bb = *reinterpret_cast<const short8*>(&Bl[w * 64 + nt * 16 + r][ks * 32 + g * 8]);
        acc[0][nt] = __builtin_amdgcn_mfma_f32_16x16x32_bf16(af0, bb, acc[0][nt], 0, 0, 0);
        acc[1][nt] = __builtin_amdgcn_mfma_f32_16x16x32_bf16(af1, bb, acc[1][nt], 0, 0, 0);
      }
    }
  }
#pragma unroll
  for (int rt = 0; rt < 2; rt++)
#pragma unroll
    for (int nt = 0; nt < 4; nt++)
#pragma unroll
      for (int j = 0; j < 4; j++)
        Cl[rt * 16 + g * 4 + j][w * 64 + nt * 16 + r] = acc[rt][nt][j];
  __syncthreads();
  int row = tid >> 3, sub = tid & 7;
  int mm = m0 + row;
  float x[32];
  float sum = 0.f, sumsq = 0.f;
#pragma unroll
  for (int i = 0; i < 8; i++) {
    int col = sub * 32 + i * 4;
    float4 xv = *reinterpret_cast<const float4*>(X + mm * SD + col);
    float4 bb = *reinterpret_cast<const float4*>(bfv + col);
    x[i * 4 + 0] = Cl[row][col + 0] + xv.x + bb.x;
    x[i * 4 + 1] = Cl[row][col + 1] + xv.y + bb.y;
    x[i * 4 + 2] = Cl[row][col + 2] + xv.z + bb.z;
    x[i * 4 + 3] = Cl[row][col + 3] + xv.w + bb.w;
  }
#pragma unroll
  for (int c = 0; c < 32; c++) { sum += x[c]; sumsq += x[c] * x[c]; }
  sum += __shfl_xor(sum, 1);  sumsq += __shfl_xor(sumsq, 1);
  sum += __shfl_xor(sum, 2);  sumsq += __shfl_xor(sumsq, 2);
  sum += __shfl_xor(sum, 4);  sumsq += __shfl_xor(sumsq, 4);
  float mean = sum * (1.0f / 256.0f);
  float var = sumsq * (1.0f / 256.0f) - mean * mean;
  float rstd = rsqrtf(var + 1e-6f);
#pragma unroll
  for (int i = 0; i < 8; i++) {
    int col = sub * 32 + i * 4;
    float4 gv = *reinterpret_cast<const float4*>(gamma + col);
    float4 bv2 = *reinterpret_cast<const float4*>(beta + col);
    float4 ov;
    ov.x = (x[i * 4 + 0] - mean) * rstd * gv.x + bv2.x;
    ov.y = (x[i * 4 + 1] - mean) * rstd * gv.y + bv2.y;
    ov.z = (x[i * 4 + 2] - mean) * rstd * gv.z + bv2.z;
    ov.w = (x[i * 4 + 3] - mean) * rstd * gv.w + bv2.w;
    *reinterpret_cast<float4*>(out + mm * SD + col) = ov;
  }
}

extern "C" void kernel_launch(void* const* d_in, const int* in_sizes, int n_in,
                              void* d_out, int out_size, void* d_ws, size_t ws_size,
                              hipStream_t stream) {
  const float* X  = (const float*)d_in[0];
  const float* Wq = (const float*)d_in[1];
  const float* Wk = (const float*)d_in[2];
  const float* Wv = (const float*)d_in[3];
  const float* Wf = (const float*)d_in[4];
  const float* bf = (const float*)d_in[5];
  const float* gm = (const float*)d_in[6];
  const float* bt = (const float*)d_in[7];
  float* out = (float*)d_out;
  unsigned short* ws = (unsigned short*)d_ws;

  qkv_k<<<dim3(64, 6), 256, 0, stream>>>(X, Wq, Wk, Wv, ws);
  attn_k<<<dim3(1024), 512, 0, stream>>>(ws, ws);
  final_k<<<256, 256, 0, stream>>>(ws, X, Wf, bf, gm, bt, out);
}

// Round 10
// 58.942 us; speedup vs baseline: 1.0954x; 1.0954x over previous
//
#include <hip/hip_runtime.h>
#include <hip/hip_bf16.h>

typedef __attribute__((ext_vector_type(8))) short short8;
typedef __attribute__((ext_vector_type(4))) float f32x4;
typedef __attribute__((ext_vector_type(16))) float f32x16;

#define DEVI __device__ __forceinline__

DEVI unsigned short f2bf(float f) {
  union { float f; unsigned int u; } v; v.f = f;
  unsigned int r = v.u + 0x7fffu + ((v.u >> 16) & 1u);
  return (unsigned short)(r >> 16);
}

DEVI unsigned int cvt2(float lo, float hi) {  // v_cvt_pk_bf16_f32 (RNE)
  unsigned int r;
  asm("v_cvt_pk_bf16_f32 %0, %1, %2" : "=v"(r) : "v"(lo), "v"(hi));
  return r;
}

// direct global->LDS, 16B per lane. dest = wave-uniform base + lane*16 (linear).
#define GLDS16(gp, lp)                                                         \
  __builtin_amdgcn_global_load_lds(                                            \
      (const __attribute__((address_space(1))) unsigned int*)(uintptr_t)(gp),  \
      (__attribute__((address_space(3))) unsigned int*)(uintptr_t)(lp), 16, 0, 0)

// problem sizes
#define SB 4
#define SS 2048
#define SD 256
#define SH 8
#define SDH 32
#define SM 8192  // B*S

// softmax scale folded into Q:  (1/sqrt(S)) * log2(e)
#define QSCALE 0.0318793654f

// workspace layout (ushort element offsets) -- all bf16 intermediates
#define Q_OFF   0                 // [BH][S][dh]   (Q pre-scaled by QSCALE)
#define K_OFF   (SM * SD)         // [BH][S][dh]
#define VT_OFF  (2 * SM * SD)     // [BH][dh][S]  (V transposed)
#define AO_OFF  (3 * SM * SD)     // [M][D] attention output

// ---------------- kernel 1: fused convert + QKV projection, 128x128 tile ----
// (byte-identical to the 58.8us config)
__global__ __launch_bounds__(256) void qkv_k(
    const float* __restrict__ X, const float* __restrict__ Wq,
    const float* __restrict__ Wk, const float* __restrict__ Wv,
    unsigned short* __restrict__ ws) {
  __shared__ __align__(16) unsigned short Atile[128][72];
  __shared__ __align__(16) unsigned short Btile[128][72];
  int tid = threadIdx.x, w = tid >> 6, lane = tid & 63, g = lane >> 4, r = lane & 15;
  int m0 = blockIdx.x * 128, n0 = blockIdx.y * 128;
  int z = n0 >> 8, nbase = n0 & 255;
  const float* Wz = (z == 0) ? Wq : (z == 1) ? Wk : Wv;
  int wr = (w >> 1) * 64, wc = (w & 1) * 64;
  f32x4 acc[4][4] = {};
  int srow = tid >> 3, scol = (tid & 7) * 8;
  float4 a0[4], a1[4], b0[4], b1[4];
#pragma unroll
  for (int p = 0; p < 4; ++p) {
    const float* xa = X + (m0 + srow + p * 32) * SD + scol;
    const float* xb = Wz + (nbase + srow + p * 32) * SD + scol;
    a0[p] = *reinterpret_cast<const float4*>(xa);
    a1[p] = *reinterpret_cast<const float4*>(xa + 4);
    b0[p] = *reinterpret_cast<const float4*>(xb);
    b1[p] = *reinterpret_cast<const float4*>(xb + 4);
  }
  for (int k0 = 0; k0 < SD; k0 += 64) {
    __syncthreads();
#pragma unroll
    for (int p = 0; p < 4; ++p) {
      uint4 ua = { cvt2(a0[p].x, a0[p].y), cvt2(a0[p].z, a0[p].w),
                   cvt2(a1[p].x, a1[p].y), cvt2(a1[p].z, a1[p].w) };
      uint4 ub = { cvt2(b0[p].x, b0[p].y), cvt2(b0[p].z, b0[p].w),
                   cvt2(b1[p].x, b1[p].y), cvt2(b1[p].z, b1[p].w) };
      *reinterpret_cast<uint4*>(&Atile[srow + p * 32][scol]) = ua;
      *reinterpret_cast<uint4*>(&Btile[srow + p * 32][scol]) = ub;
    }
    __syncthreads();
    if (k0 + 64 < SD) {
#pragma unroll
      for (int p = 0; p < 4; ++p) {
        const float* xa = X + (m0 + srow + p * 32) * SD + k0 + 64 + scol;
        const float* xb = Wz + (nbase + srow + p * 32) * SD + k0 + 64 + scol;
        a0[p] = *reinterpret_cast<const float4*>(xa);
        a1[p] = *reinterpret_cast<const float4*>(xa + 4);
        b0[p] = *reinterpret_cast<const float4*>(xb);
        b1[p] = *reinterpret_cast<const float4*>(xb + 4);
      }
    }
#pragma unroll
    for (int ks = 0; ks < 2; ++ks) {
      short8 af[4], bf[4];
#pragma unroll
      for (int i = 0; i < 4; ++i)
        af[i] = *reinterpret_cast<const short8*>(&Atile[wr + i * 16 + r][ks * 32 + g * 8]);
#pragma unroll
      for (int j = 0; j < 4; ++j)
        bf[j] = *reinterpret_cast<const short8*>(&Btile[wc + j * 16 + r][ks * 32 + g * 8]);
#pragma unroll
      for (int i = 0; i < 4; ++i)
#pragma unroll
        for (int j = 0; j < 4; ++j)
          acc[i][j] = __builtin_amdgcn_mfma_f32_16x16x32_bf16(af[i], bf[j], acc[i][j], 0, 0, 0);
    }
  }
  int b_ = m0 >> 11, sbase = m0 & 2047;
  float qs = (z == 0) ? QSCALE : 1.0f;
  unsigned short* Vt = &Btile[0][0];  // reused as [64][136]
#pragma unroll
  for (int p = 0; p < 2; ++p) {       // n-half pass: cols p*64 .. p*64+63
    __syncthreads();
    if ((w & 1) == p) {
      if (z < 2) {
#pragma unroll
        for (int i = 0; i < 4; ++i)
#pragma unroll
          for (int j = 0; j < 4; ++j)
#pragma unroll
            for (int jj = 0; jj < 4; ++jj)
              Atile[wr + i * 16 + g * 4 + jj][j * 16 + r] = f2bf(acc[i][j][jj] * qs);
      } else {
#pragma unroll
        for (int i = 0; i < 4; ++i)
#pragma unroll
          for (int j = 0; j < 4; ++j) {
            unsigned short o4[4];
#pragma unroll
            for (int jj = 0; jj < 4; ++jj) o4[jj] = f2bf(acc[i][j][jj]);
            *reinterpret_cast<uint2*>(&Vt[(j * 16 + r) * 136 + wr + i * 16 + g * 4]) =
                *reinterpret_cast<const uint2*>(o4);
          }
      }
    }
    __syncthreads();
    if (z < 2) {
      unsigned short* out = ws + (z == 0 ? Q_OFF : K_OFF);
      int h0 = (nbase + p * 64) >> 5;
#pragma unroll
      for (int it = 0; it < 4; ++it) {
        int c = it * 256 + tid;                  // 1024 chunks of 16B
        int m = c >> 3, cr = c & 7, hl = cr >> 2, ch = cr & 3;
        short8 val = *reinterpret_cast<const short8*>(&Atile[m][hl * 32 + ch * 8]);
        int h = h0 + hl;
        *reinterpret_cast<short8*>(
            out + (((b_ << 3) + h) * SS + sbase + m) * SDH + ch * 8) = val;
      }
    } else {
      unsigned short* out = ws + VT_OFF;
      int nb = nbase + p * 64;
#pragma unroll
      for (int it = 0; it < 4; ++it) {
        int c = it * 256 + tid;                  // 1024 chunks of 16B
        int nl = c >> 4, ch = c & 15;
        short8 val = *reinterpret_cast<const short8*>(&Vt[nl * 136 + ch * 8]);
        int col = nb + nl, h = col >> 5, d = col & 31;
        *reinterpret_cast<short8*>(
            out + ((((b_ << 3) + h) << 5) + d) * SS + sbase + ch * 8) = val;
      }
    }
  }
}

// ---------------- kernel 2: flash attention, wave-phase-staggered ----------------
// 512 blocks (32 bh x 16 qb, XCD-swizzled) x 512 thr = 8 waves.
// Waves 0-3: kv [0,1024), waves 4-7: kv [1024,2048); each wave 32 q rows.
// TKV=128 per barrier pair, dbuf global_load_lds, counted vmcnt(4).
// NEW: per-wave ROTATED subtile order s = (si + wl) & 3 -- legal because
// fixed-M softmax accumulation is order-free and all waves read the same
// staged tile. Breaks the block-wide phase lock (R5: 30% no-issue with all
// waves demanding the same pipe simultaneously); setprio(1) on MFMA clusters
// now has cross-phase waves to arbitrate between (m191 mechanism).
__global__ __launch_bounds__(512, 4) void attn_k(const unsigned short* __restrict__ ws_c,
                                                 unsigned short* __restrict__ ws) {
  __shared__ __align__(16) unsigned char smem[65536];
  int tid = threadIdx.x, w = tid >> 6, lane = tid & 63;
  int wg = w >> 2, wl = w & 3, gtid = tid & 255;
  int n32 = lane & 31, hi = lane >> 5;
  // XCD-aware swizzle (512 % 8 == 0 -> bijective)
  int wgid = ((blockIdx.x & 7) << 6) + (blockIdx.x >> 3);
  int bh = wgid >> 4, qb = wgid & 15;
  int q0 = qb * 128 + wl * 32;
  const unsigned short* Qh = ws_c + Q_OFF + bh * (SS * SDH);
  const unsigned short* Kg = ws_c + K_OFF + (bh * SS + wg * 1024) * SDH;
  const unsigned short* Vg = ws_c + VT_OFF + bh * (SDH * SS) + wg * 1024;
  // Q B-frags: lane holds col q=n32, k = 8*hi + j (dh halves)
  short8 qB0 = *reinterpret_cast<const short8*>(Qh + (q0 + n32) * SDH + 8 * hi);
  short8 qB1 = *reinterpret_cast<const short8*>(Qh + (q0 + n32) * SDH + 16 + 8 * hi);
  // LDS regions: K[grp][buf] 8KB each; V[grp][buf] 8KB each
  unsigned short* Kbuf0 = (unsigned short*)(smem + wg * 16384);
  unsigned short* Kbuf1 = (unsigned short*)(smem + wg * 16384 + 8192);
  unsigned short* Vbuf0 = (unsigned short*)(smem + 32768 + wg * 16384);
  unsigned short* Vbuf1 = (unsigned short*)(smem + 32768 + wg * 16384 + 8192);
  int wv = gtid >> 6;  // wave index within 256-thread group (wave-uniform)
  // staging sources (inverse-swizzled so linear LDS dest ends up swizzled)
  int kr = gtid >> 2;
  int kcg = (gtid & 3) ^ ((kr >> 1) & 3);
  const unsigned short* gK0 = Kg + kr * SDH + kcg * 8;   // rows 0-63 of tile
  const unsigned short* gK1 = gK0 + 64 * SDH;            // rows 64-127
  int vr = gtid >> 4;
  int vcg = (gtid & 15) ^ (vr & 7);
  const unsigned short* gV0 = Vg + vr * SS + vcg * 8;    // d rows 0-15
  const unsigned short* gV1 = gV0 + 16 * SS;             // d rows 16-31
  auto issue = [&](int buf, int tt) {
    char* kd = (char*)(buf ? Kbuf1 : Kbuf0) + wv * 1024;
    char* vd = (char*)(buf ? Vbuf1 : Vbuf0) + wv * 1024;
    GLDS16(gK0 + tt * 4096, kd);
    GLDS16(gK1 + tt * 4096, kd + 4096);
    GLDS16(gV0 + tt * 128, vd);
    GLDS16(gV1 + tt * 128, vd + 4096);
  };
  issue(0, 0);
  f32x16 O = {}, Lf = {};
  union { unsigned int u[4]; short8 sv; } ONES;
  ONES.u[0] = 0x3F803F80u; ONES.u[1] = 0x3F803F80u;
  ONES.u[2] = 0x3F803F80u; ONES.u[3] = 0x3F803F80u;
  // read-side swizzle constants
  int rb = (n32 >> 1) & 3;
  int koff0 = (hi ^ rb) * 8;          // K logical chunk l=hi
  int koff1 = ((2 + hi) ^ rb) * 8;    // K logical chunk l=2+hi
  int vb7 = n32 & 7;
  for (int t = 0; t < 8; ++t) {
    const unsigned short* Kt = (t & 1) ? Kbuf1 : Kbuf0;
    const unsigned short* Vt = (t & 1) ? Vbuf1 : Vbuf0;
    if (t < 7) {
      issue((t + 1) & 1, t + 1);
      asm volatile("s_waitcnt vmcnt(4)" ::: "memory");  // tile t landed; t+1 in flight
    } else {
      asm volatile("s_waitcnt vmcnt(0)" ::: "memory");
    }
    __builtin_amdgcn_s_barrier();
#pragma unroll
    for (int si = 0; si < 4; ++si) {
      int s = (si + wl) & 3;  // per-wave phase stagger
      const unsigned short* krow = Kt + (s * 32 + n32) * 32;
      short8 ka = *reinterpret_cast<const short8*>(krow + koff0);
      short8 kb = *reinterpret_cast<const short8*>(krow + koff1);
      f32x16 aC = {};
      __builtin_amdgcn_s_setprio(1);
      aC = __builtin_amdgcn_mfma_f32_32x32x16_bf16(ka, qB0, aC, 0, 0, 0);
      aC = __builtin_amdgcn_mfma_f32_32x32x16_bf16(kb, qB1, aC, 0, 0, 0);
      __builtin_amdgcn_s_setprio(0);
      // p = exp2(s); lane holds kv(reg,hi) = (reg&3) + 8*(reg>>2) + 4*hi
#pragma unroll
      for (int i = 0; i < 16; ++i) aC[i] = __builtin_amdgcn_exp2f(aC[i]);
      // P -> PV A-frags via cvt_pk + permlane32_swap (derived+verified R1)
      unsigned int pk[8];
#pragma unroll
      for (int i = 0; i < 8; ++i) pk[i] = cvt2(aC[2 * i], aC[2 * i + 1]);
      asm("v_permlane32_swap_b32 %0, %1" : "+v"(pk[0]), "+v"(pk[2]));
      asm("v_permlane32_swap_b32 %0, %1" : "+v"(pk[1]), "+v"(pk[3]));
      asm("v_permlane32_swap_b32 %0, %1" : "+v"(pk[4]), "+v"(pk[6]));
      asm("v_permlane32_swap_b32 %0, %1" : "+v"(pk[5]), "+v"(pk[7]));
      union { unsigned int u[4]; short8 sv; } A1, A2;
      A1.u[0] = pk[0]; A1.u[1] = pk[1]; A1.u[2] = pk[2]; A1.u[3] = pk[3];
      A2.u[0] = pk[4]; A2.u[1] = pk[5]; A2.u[2] = pk[6]; A2.u[3] = pk[7];
      const unsigned short* vrow = Vt + n32 * 128;
      short8 vB0 = *reinterpret_cast<const short8*>(vrow + ((s * 4 + hi) ^ vb7) * 8);
      short8 vB1 = *reinterpret_cast<const short8*>(vrow + ((s * 4 + 2 + hi) ^ vb7) * 8);
      __builtin_amdgcn_s_setprio(1);
      O  = __builtin_amdgcn_mfma_f32_32x32x16_bf16(A1.sv, vB0, O, 0, 0, 0);
      O  = __builtin_amdgcn_mfma_f32_32x32x16_bf16(A2.sv, vB1, O, 0, 0, 0);
      Lf = __builtin_amdgcn_mfma_f32_32x32x16_bf16(A1.sv, ONES.sv, Lf, 0, 0, 0);
      Lf = __builtin_amdgcn_mfma_f32_32x32x16_bf16(A2.sv, ONES.sv, Lf, 0, 0, 0);
      __builtin_amdgcn_s_setprio(0);
    }
    __builtin_amdgcn_s_barrier();
  }
  // combine the two kv-groups (fixed-M softmax -> O,L add linearly).
  // Conflict-free layout: OC[i][p] row-major, p = wl*64+lane consecutive.
  __syncthreads();
  float* OCf = reinterpret_cast<float*>(smem);           // [16][257]
  float* LCf = OCf + 16 * 257;                           // [16][257]
  int p = wl * 64 + lane;
  if (wg == 1) {
#pragma unroll
    for (int i = 0; i < 16; ++i) { OCf[i * 257 + p] = O[i]; LCf[i * 257 + p] = Lf[i]; }
  }
  __syncthreads();
  if (wg == 0) {
    int b = bh >> 3, h = bh & 7;
    unsigned short* AO = ws + AO_OFF;
#pragma unroll
    for (int rr = 0; rr < 16; ++rr) {
      float Ot = O[rr] + OCf[rr * 257 + p];
      float Lt = Lf[rr] + LCf[rr * 257 + p];
      int q = (rr & 3) + 8 * (rr >> 2) + 4 * hi;
      AO[(b * SS + q0 + q) * SD + h * SDH + n32] = f2bf(Ot / Lt);
    }
  }
}

// ---------------- kernel 3: out-proj + bias + residual + LayerNorm ----------
// (byte-identical to the 58.8us config)
__global__ __launch_bounds__(256) void final_k(
    const unsigned short* __restrict__ ws_c, const float* __restrict__ X,
    const float* __restrict__ Wf, const float* __restrict__ bfv,
    const float* __restrict__ gamma, const float* __restrict__ beta,
    float* __restrict__ out) {
  __shared__ __align__(16) unsigned short Al[32][72];
  __shared__ __align__(16) unsigned short Bl[256][72];
  __shared__ float Cl[32][257];
  const unsigned short* AO = ws_c + AO_OFF;
  int tid = threadIdx.x, w = tid >> 6, lane = tid & 63, g = lane >> 4, r = lane & 15;
  int m0 = blockIdx.x * 32;
  f32x4 acc[2][4] = {};
  int arow = tid >> 3, acol = (tid & 7) * 8;
  for (int k0 = 0; k0 < SD; k0 += 64) {
    short8 av = *reinterpret_cast<const short8*>(AO + (m0 + arow) * SD + k0 + acol);
    float4 w0[8], w1[8];
#pragma unroll
    for (int i = 0; i < 8; i++) {
      const float* wp = Wf + (i * 32 + arow) * SD + k0 + acol;
      w0[i] = *reinterpret_cast<const float4*>(wp);
      w1[i] = *reinterpret_cast<const float4*>(wp + 4);
    }
    __syncthreads();
    *reinterpret_cast<short8*>(&Al[arow][acol]) = av;
#pragma unroll
    for (int i = 0; i < 8; i++) {
      uint4 ub = { cvt2(w0[i].x, w0[i].y), cvt2(w0[i].z, w0[i].w),
                   cvt2(w1[i].x, w1[i].y), cvt2(w1[i].z, w1[i].w) };
      *reinterpret_cast<uint4*>(&Bl[i * 32 + arow][acol]) = ub;
    }
    __syncthreads();
#pragma unroll
    for (int ks = 0; ks < 2; ks++) {
      short8 af0 = *reinterpret_cast<const short8*>(&Al[r][ks * 32 + g * 8]);
      short8 af1 = *reinterpret_cast<const short8*>(&Al[16 + r][ks * 32 + g * 8]);
#pragma unroll
      for (int nt = 0; nt < 4; nt++) {
        short8 bb = *reinterpret_cast<const short8*>(&Bl[w * 64 + nt * 16 + r][ks * 32 + g * 8]);
        acc[0][nt] = __builtin_amdgcn_mfma_f32_16x16x32_bf16(af0, bb, acc[0][nt], 0, 0, 0);
        acc[1][nt] = __builtin_amdgcn_mfma_f32_16x16x32_bf16(af1, bb, acc[1][nt], 0, 0, 0);
      }
    }
  }
#pragma unroll
  for (int rt = 0; rt < 2; rt++)
#pragma unroll
    for (int nt = 0; nt < 4; nt++)
#pragma unroll
      for (int j = 0; j < 4; j++)
        Cl[rt * 16 + g * 4 + j][w * 64 + nt * 16 + r] = acc[rt][nt][j];
  __syncthreads();
  int row = tid >> 3, sub = tid & 7;
  int m = m0 + row;
  float x[32];
  float sum = 0.f, sumsq = 0.f;
#pragma unroll
  for (int i = 0; i < 8; i++) {
    int col = sub * 32 + i * 4;
    float4 xv = *reinterpret_cast<const float4*>(X + m * SD + col);
    float4 bb = *reinterpret_cast<const float4*>(bfv + col);
    x[i * 4 + 0] = Cl[row][col + 0] + xv.x + bb.x;
    x[i * 4 + 1] = Cl[row][col + 1] + xv.y + bb.y;
    x[i * 4 + 2] = Cl[row][col + 2] + xv.z + bb.z;
    x[i * 4 + 3] = Cl[row][col + 3] + xv.w + bb.w;
  }
#pragma unroll
  for (int c = 0; c < 32; c++) { sum += x[c]; sumsq += x[c] * x[c]; }
  sum += __shfl_xor(sum, 1);  sumsq += __shfl_xor(sumsq, 1);
  sum += __shfl_xor(sum, 2);  sumsq += __shfl_xor(sumsq, 2);
  sum += __shfl_xor(sum, 4);  sumsq += __shfl_xor(sumsq, 4);
  float mean = sum * (1.0f / 256.0f);
  float var = sumsq * (1.0f / 256.0f) - mean * mean;
  float rstd = rsqrtf(var + 1e-6f);
#pragma unroll
  for (int i = 0; i < 8; i++) {
    int col = sub * 32 + i * 4;
    float4 gv = *reinterpret_cast<const float4*>(gamma + col);
    float4 bv2 = *reinterpret_cast<const float4*>(beta + col);
    float4 ov;
    ov.x = (x[i * 4 + 0] - mean) * rstd * gv.x + bv2.x;
    ov.y = (x[i * 4 + 1] - mean) * rstd * gv.y + bv2.y;
    ov.z = (x[i * 4 + 2] - mean) * rstd * gv.z + bv2.z;
    ov.w = (x[i * 4 + 3] - mean) * rstd * gv.w + bv2.w;
    *reinterpret_cast<float4*>(out + m * SD + col) = ov;
  }
}

extern "C" void kernel_launch(void* const* d_in, const int* in_sizes, int n_in,
                              void* d_out, int out_size, void* d_ws, size_t ws_size,
                              hipStream_t stream) {
  const float* X  = (const float*)d_in[0];
  const float* Wq = (const float*)d_in[1];
  const float* Wk = (const float*)d_in[2];
  const float* Wv = (const float*)d_in[3];
  const float* Wf = (const float*)d_in[4];
  const float* bf = (const float*)d_in[5];
  const float* gm = (const float*)d_in[6];
  const float* bt = (const float*)d_in[7];
  float* out = (float*)d_out;
  unsigned short* ws = (unsigned short*)d_ws;

  qkv_k<<<dim3(64, 6), 256, 0, stream>>>(X, Wq, Wk, Wv, ws);
  attn_k<<<dim3(512), 512, 0, stream>>>(ws, ws);
  final_k<<<256, 256, 0, stream>>>(ws, X, Wf, bf, gm, bt, out);
}

// Round 11
// 54.946 us; speedup vs baseline: 1.1751x; 1.0727x over previous
//
#include <hip/hip_runtime.h>
#include <hip/hip_bf16.h>

typedef __attribute__((ext_vector_type(8))) short short8;
typedef __attribute__((ext_vector_type(4))) float f32x4;
typedef __attribute__((ext_vector_type(16))) float f32x16;

#define DEVI __device__ __forceinline__

DEVI unsigned short f2bf(float f) {
  union { float f; unsigned int u; } v; v.f = f;
  unsigned int r = v.u + 0x7fffu + ((v.u >> 16) & 1u);
  return (unsigned short)(r >> 16);
}

DEVI unsigned int cvt2(float lo, float hi) {  // v_cvt_pk_bf16_f32 (RNE)
  unsigned int r;
  asm("v_cvt_pk_bf16_f32 %0, %1, %2" : "=v"(r) : "v"(lo), "v"(hi));
  return r;
}

// direct global->LDS, 16B per lane. dest = wave-uniform base + lane*16 (linear).
#define GLDS16(gp, lp)                                                         \
  __builtin_amdgcn_global_load_lds(                                            \
      (const __attribute__((address_space(1))) unsigned int*)(uintptr_t)(gp),  \
      (__attribute__((address_space(3))) unsigned int*)(uintptr_t)(lp), 16, 0, 0)

// problem sizes
#define SB 4
#define SS 2048
#define SD 256
#define SH 8
#define SDH 32
#define SM 8192  // B*S

// softmax scale folded into Q:  (1/sqrt(S)) * log2(e)
#define QSCALE 0.0318793654f

// workspace layout (ushort element offsets) -- all bf16 intermediates
#define Q_OFF   0                 // [BH][S][dh]   (Q pre-scaled by QSCALE)
#define K_OFF   (SM * SD)         // [BH][S][dh]
#define VT_OFF  (2 * SM * SD)     // [BH][dh][S]  (V transposed)
#define AO_OFF  (3 * SM * SD)     // [M][D] attention output
#define WF_OFF  (4 * SM * SD)     // [256][256] Wf in bf16 (converted by qkv_k)

// ---------------- kernel 1: fused convert + QKV projection, 64x128 tile -----
// Grid 128x6 = 768 blocks = EXACTLY 3/CU (was 384 = 1.5/CU -> 25% idle tail).
// z = y>>1 selects Wq/Wk/Wv; nbase = (y&1)*128. fp32 in-register convert while
// staging. Epilogue via LDS for coalesced stores. z==2 blocks additionally
// convert a 1KB slice of Wf to bf16 (for final_k) -- no extra launch.
__global__ __launch_bounds__(256) void qkv_k(
    const float* __restrict__ X, const float* __restrict__ Wq,
    const float* __restrict__ Wk, const float* __restrict__ Wv,
    const float* __restrict__ Wf, unsigned short* __restrict__ ws) {
  __shared__ __align__(16) unsigned short Atile[64][72];
  __shared__ __align__(16) unsigned short Btile[128][72];
  int tid = threadIdx.x, w = tid >> 6, lane = tid & 63, g = lane >> 4, r = lane & 15;
  int m0 = blockIdx.x * 64;
  int z = blockIdx.y >> 1, nbase = (blockIdx.y & 1) * 128;
  const float* Wz = (z == 0) ? Wq : (z == 1) ? Wk : Wv;
  if (z == 2) {  // Wf fp32 -> bf16, 256 floats per block (slice disjoint)
    int slice = blockIdx.x + (nbase ? 128 : 0);
    ws[WF_OFF + slice * 256 + tid] = f2bf(Wf[slice * 256 + tid]);
  }
  int wr = (w >> 1) * 32, wc = (w & 1) * 64;
  f32x4 acc[2][4] = {};
  int srow = tid >> 3, scol = (tid & 7) * 8;
  float4 a0[2], a1[2], b0[4], b1[4];
#pragma unroll
  for (int p = 0; p < 2; ++p) {
    const float* xa = X + (m0 + srow + p * 32) * SD + scol;
    a0[p] = *reinterpret_cast<const float4*>(xa);
    a1[p] = *reinterpret_cast<const float4*>(xa + 4);
  }
#pragma unroll
  for (int p = 0; p < 4; ++p) {
    const float* xb = Wz + (nbase + srow + p * 32) * SD + scol;
    b0[p] = *reinterpret_cast<const float4*>(xb);
    b1[p] = *reinterpret_cast<const float4*>(xb + 4);
  }
  for (int k0 = 0; k0 < SD; k0 += 64) {
    __syncthreads();
#pragma unroll
    for (int p = 0; p < 2; ++p) {
      uint4 ua = { cvt2(a0[p].x, a0[p].y), cvt2(a0[p].z, a0[p].w),
                   cvt2(a1[p].x, a1[p].y), cvt2(a1[p].z, a1[p].w) };
      *reinterpret_cast<uint4*>(&Atile[srow + p * 32][scol]) = ua;
    }
#pragma unroll
    for (int p = 0; p < 4; ++p) {
      uint4 ub = { cvt2(b0[p].x, b0[p].y), cvt2(b0[p].z, b0[p].w),
                   cvt2(b1[p].x, b1[p].y), cvt2(b1[p].z, b1[p].w) };
      *reinterpret_cast<uint4*>(&Btile[srow + p * 32][scol]) = ub;
    }
    __syncthreads();
    if (k0 + 64 < SD) {
#pragma unroll
      for (int p = 0; p < 2; ++p) {
        const float* xa = X + (m0 + srow + p * 32) * SD + k0 + 64 + scol;
        a0[p] = *reinterpret_cast<const float4*>(xa);
        a1[p] = *reinterpret_cast<const float4*>(xa + 4);
      }
#pragma unroll
      for (int p = 0; p < 4; ++p) {
        const float* xb = Wz + (nbase + srow + p * 32) * SD + k0 + 64 + scol;
        b0[p] = *reinterpret_cast<const float4*>(xb);
        b1[p] = *reinterpret_cast<const float4*>(xb + 4);
      }
    }
#pragma unroll
    for (int ks = 0; ks < 2; ++ks) {
      short8 af[2], bf[4];
#pragma unroll
      for (int i = 0; i < 2; ++i)
        af[i] = *reinterpret_cast<const short8*>(&Atile[wr + i * 16 + r][ks * 32 + g * 8]);
#pragma unroll
      for (int j = 0; j < 4; ++j)
        bf[j] = *reinterpret_cast<const short8*>(&Btile[wc + j * 16 + r][ks * 32 + g * 8]);
#pragma unroll
      for (int i = 0; i < 2; ++i)
#pragma unroll
        for (int j = 0; j < 4; ++j)
          acc[i][j] = __builtin_amdgcn_mfma_f32_16x16x32_bf16(af[i], bf[j], acc[i][j], 0, 0, 0);
    }
  }
  int b_ = m0 >> 11, sbase = m0 & 2047;
  float qs = (z == 0) ? QSCALE : 1.0f;
  unsigned short* Vt = &Btile[0][0];  // reused as [64 n][80 m-pad] (160B rows: 16B-aligned)
#pragma unroll
  for (int p = 0; p < 2; ++p) {       // n-half pass: local cols p*64 .. p*64+63
    __syncthreads();
    if ((w & 1) == p) {
      if (z < 2) {
#pragma unroll
        for (int i = 0; i < 2; ++i)
#pragma unroll
          for (int j = 0; j < 4; ++j)
#pragma unroll
            for (int jj = 0; jj < 4; ++jj)
              Atile[wr + i * 16 + g * 4 + jj][j * 16 + r] = f2bf(acc[i][j][jj] * qs);
      } else {
#pragma unroll
        for (int i = 0; i < 2; ++i)
#pragma unroll
          for (int j = 0; j < 4; ++j) {
            unsigned short o4[4];
#pragma unroll
            for (int jj = 0; jj < 4; ++jj) o4[jj] = f2bf(acc[i][j][jj]);
            *reinterpret_cast<uint2*>(&Vt[(j * 16 + r) * 80 + wr + i * 16 + g * 4]) =
                *reinterpret_cast<const uint2*>(o4);
          }
      }
    }
    __syncthreads();
    if (z < 2) {
      unsigned short* out = ws + (z == 0 ? Q_OFF : K_OFF);
      int h0 = (nbase + p * 64) >> 5;
#pragma unroll
      for (int it = 0; it < 2; ++it) {
        int c = it * 256 + tid;                  // 512 chunks of 16B
        int m = c >> 3, cr = c & 7, hl = cr >> 2, ch = cr & 3;
        short8 val = *reinterpret_cast<const short8*>(&Atile[m][hl * 32 + ch * 8]);
        int h = h0 + hl;
        *reinterpret_cast<short8*>(
            out + (((b_ << 3) + h) * SS + sbase + m) * SDH + ch * 8) = val;
      }
    } else {
      unsigned short* out = ws + VT_OFF;
      int nb = nbase + p * 64;
#pragma unroll
      for (int it = 0; it < 2; ++it) {
        int c = it * 256 + tid;                  // 512 chunks of 16B
        int nl = c >> 3, ch = c & 7;
        short8 val = *reinterpret_cast<const short8*>(&Vt[nl * 80 + ch * 8]);
        int col = nb + nl, h = col >> 5, d = col & 31;
        *reinterpret_cast<short8*>(
            out + ((((b_ << 3) + h) << 5) + d) * SS + sbase + ch * 8) = val;
      }
    }
  }
}

// ---------------- kernel 2: flash attention (byte-identical to R9) ----------
__global__ __launch_bounds__(512, 4) void attn_k(const unsigned short* __restrict__ ws_c,
                                                 unsigned short* __restrict__ ws) {
  __shared__ __align__(16) unsigned char smem[65536];
  int tid = threadIdx.x, w = tid >> 6, lane = tid & 63;
  int wg = w >> 2, wl = w & 3, gtid = tid & 255;
  int n32 = lane & 31, hi = lane >> 5;
  int wgid = ((blockIdx.x & 7) << 6) + (blockIdx.x >> 3);
  int bh = wgid >> 4, qb = wgid & 15;
  int q0 = qb * 128 + wl * 32;
  const unsigned short* Qh = ws_c + Q_OFF + bh * (SS * SDH);
  const unsigned short* Kg = ws_c + K_OFF + (bh * SS + wg * 1024) * SDH;
  const unsigned short* Vg = ws_c + VT_OFF + bh * (SDH * SS) + wg * 1024;
  short8 qB0 = *reinterpret_cast<const short8*>(Qh + (q0 + n32) * SDH + 8 * hi);
  short8 qB1 = *reinterpret_cast<const short8*>(Qh + (q0 + n32) * SDH + 16 + 8 * hi);
  unsigned short* Kbuf0 = (unsigned short*)(smem + wg * 16384);
  unsigned short* Kbuf1 = (unsigned short*)(smem + wg * 16384 + 8192);
  unsigned short* Vbuf0 = (unsigned short*)(smem + 32768 + wg * 16384);
  unsigned short* Vbuf1 = (unsigned short*)(smem + 32768 + wg * 16384 + 8192);
  int wv = gtid >> 6;
  int kr = gtid >> 2;
  int kcg = (gtid & 3) ^ ((kr >> 1) & 3);
  const unsigned short* gK0 = Kg + kr * SDH + kcg * 8;
  const unsigned short* gK1 = gK0 + 64 * SDH;
  int vr = gtid >> 4;
  int vcg = (gtid & 15) ^ (vr & 7);
  const unsigned short* gV0 = Vg + vr * SS + vcg * 8;
  const unsigned short* gV1 = gV0 + 16 * SS;
  auto issue = [&](int buf, int tt) {
    char* kd = (char*)(buf ? Kbuf1 : Kbuf0) + wv * 1024;
    char* vd = (char*)(buf ? Vbuf1 : Vbuf0) + wv * 1024;
    GLDS16(gK0 + tt * 4096, kd);
    GLDS16(gK1 + tt * 4096, kd + 4096);
    GLDS16(gV0 + tt * 128, vd);
    GLDS16(gV1 + tt * 128, vd + 4096);
  };
  issue(0, 0);
  f32x16 O = {}, Lf = {};
  union { unsigned int u[4]; short8 sv; } ONES;
  ONES.u[0] = 0x3F803F80u; ONES.u[1] = 0x3F803F80u;
  ONES.u[2] = 0x3F803F80u; ONES.u[3] = 0x3F803F80u;
  int rb = (n32 >> 1) & 3;
  int koff0 = (hi ^ rb) * 8;
  int koff1 = ((2 + hi) ^ rb) * 8;
  int vb7 = n32 & 7;
  for (int t = 0; t < 8; ++t) {
    const unsigned short* Kt = (t & 1) ? Kbuf1 : Kbuf0;
    const unsigned short* Vt = (t & 1) ? Vbuf1 : Vbuf0;
    if (t < 7) {
      issue((t + 1) & 1, t + 1);
      asm volatile("s_waitcnt vmcnt(4)" ::: "memory");
    } else {
      asm volatile("s_waitcnt vmcnt(0)" ::: "memory");
    }
    __builtin_amdgcn_s_barrier();
#pragma unroll
    for (int si = 0; si < 4; ++si) {
      int s = (si + wl) & 3;
      const unsigned short* krow = Kt + (s * 32 + n32) * 32;
      short8 ka = *reinterpret_cast<const short8*>(krow + koff0);
      short8 kb = *reinterpret_cast<const short8*>(krow + koff1);
      f32x16 aC = {};
      __builtin_amdgcn_s_setprio(1);
      aC = __builtin_amdgcn_mfma_f32_32x32x16_bf16(ka, qB0, aC, 0, 0, 0);
      aC = __builtin_amdgcn_mfma_f32_32x32x16_bf16(kb, qB1, aC, 0, 0, 0);
      __builtin_amdgcn_s_setprio(0);
#pragma unroll
      for (int i = 0; i < 16; ++i) aC[i] = __builtin_amdgcn_exp2f(aC[i]);
      unsigned int pk[8];
#pragma unroll
      for (int i = 0; i < 8; ++i) pk[i] = cvt2(aC[2 * i], aC[2 * i + 1]);
      asm("v_permlane32_swap_b32 %0, %1" : "+v"(pk[0]), "+v"(pk[2]));
      asm("v_permlane32_swap_b32 %0, %1" : "+v"(pk[1]), "+v"(pk[3]));
      asm("v_permlane32_swap_b32 %0, %1" : "+v"(pk[4]), "+v"(pk[6]));
      asm("v_permlane32_swap_b32 %0, %1" : "+v"(pk[5]), "+v"(pk[7]));
      union { unsigned int u[4]; short8 sv; } A1, A2;
      A1.u[0] = pk[0]; A1.u[1] = pk[1]; A1.u[2] = pk[2]; A1.u[3] = pk[3];
      A2.u[0] = pk[4]; A2.u[1] = pk[5]; A2.u[2] = pk[6]; A2.u[3] = pk[7];
      const unsigned short* vrow = Vt + n32 * 128;
      short8 vB0 = *reinterpret_cast<const short8*>(vrow + ((s * 4 + hi) ^ vb7) * 8);
      short8 vB1 = *reinterpret_cast<const short8*>(vrow + ((s * 4 + 2 + hi) ^ vb7) * 8);
      __builtin_amdgcn_s_setprio(1);
      O  = __builtin_amdgcn_mfma_f32_32x32x16_bf16(A1.sv, vB0, O, 0, 0, 0);
      O  = __builtin_amdgcn_mfma_f32_32x32x16_bf16(A2.sv, vB1, O, 0, 0, 0);
      Lf = __builtin_amdgcn_mfma_f32_32x32x16_bf16(A1.sv, ONES.sv, Lf, 0, 0, 0);
      Lf = __builtin_amdgcn_mfma_f32_32x32x16_bf16(A2.sv, ONES.sv, Lf, 0, 0, 0);
      __builtin_amdgcn_s_setprio(0);
    }
    __builtin_amdgcn_s_barrier();
  }
  __syncthreads();
  float* OCf = reinterpret_cast<float*>(smem);           // [16][257]
  float* LCf = OCf + 16 * 257;                           // [16][257]
  int p = wl * 64 + lane;
  if (wg == 1) {
#pragma unroll
    for (int i = 0; i < 16; ++i) { OCf[i * 257 + p] = O[i]; LCf[i * 257 + p] = Lf[i]; }
  }
  __syncthreads();
  if (wg == 0) {
    int b = bh >> 3, h = bh & 7;
    unsigned short* AO = ws + AO_OFF;
#pragma unroll
    for (int rr = 0; rr < 16; ++rr) {
      float Ot = O[rr] + OCf[rr * 257 + p];
      float Lt = Lf[rr] + LCf[rr * 257 + p];
      int q = (rr & 3) + 8 * (rr >> 2) + 4 * hi;
      AO[(b * SS + q0 + q) * SD + h * SDH + n32] = f2bf(Ot / Lt);
    }
  }
}

// ---------------- kernel 3: out-proj + bias + residual + LayerNorm ----------
// 16-row blocks: grid 512 = 2/CU, 8 waves/CU (was 256 = 1/CU, 4 waves).
// Wf read as bf16 from workspace (converted by qkv_k) -- half the L2 traffic.
__global__ __launch_bounds__(256) void final_k(
    const unsigned short* __restrict__ ws_c, const float* __restrict__ X,
    const float* __restrict__ bfv, const float* __restrict__ gamma,
    const float* __restrict__ beta, float* __restrict__ out) {
  __shared__ __align__(16) unsigned short Al[16][72];
  __shared__ __align__(16) unsigned short Bl[256][72];
  __shared__ float Cl[16][257];
  const unsigned short* AO = ws_c + AO_OFF;
  const unsigned short* Wfb = ws_c + WF_OFF;
  int tid = threadIdx.x, w = tid >> 6, lane = tid & 63, g = lane >> 4, r = lane & 15;
  int m0 = blockIdx.x * 16;
  f32x4 acc[4] = {};
  int arow = tid >> 4, acol = (tid & 15) * 4;   // A: 16 rows x 64 cols, 4 elems/thread
  int brow = tid >> 3, bcol = (tid & 7) * 8;    // B: 256 rows x 64 cols, 8x short8/thread
  for (int k0 = 0; k0 < SD; k0 += 64) {
    uint2 av = *reinterpret_cast<const uint2*>(AO + (m0 + arow) * SD + k0 + acol);
    short8 bv[8];
#pragma unroll
    for (int i = 0; i < 8; i++)
      bv[i] = *reinterpret_cast<const short8*>(Wfb + (i * 32 + brow) * SD + k0 + bcol);
    __syncthreads();
    *reinterpret_cast<uint2*>(&Al[arow][acol]) = av;
#pragma unroll
    for (int i = 0; i < 8; i++)
      *reinterpret_cast<short8*>(&Bl[i * 32 + brow][bcol]) = bv[i];
    __syncthreads();
#pragma unroll
    for (int ks = 0; ks < 2; ks++) {
      short8 af = *reinterpret_cast<const short8*>(&Al[r][ks * 32 + g * 8]);
#pragma unroll
      for (int nt = 0; nt < 4; nt++) {
        short8 bb = *reinterpret_cast<const short8*>(&Bl[w * 64 + nt * 16 + r][ks * 32 + g * 8]);
        acc[nt] = __builtin_amdgcn_mfma_f32_16x16x32_bf16(af, bb, acc[nt], 0, 0, 0);
      }
    }
  }
#pragma unroll
  for (int nt = 0; nt < 4; nt++)
#pragma unroll
    for (int j = 0; j < 4; j++)
      Cl[g * 4 + j][w * 64 + nt * 16 + r] = acc[nt][j];
  __syncthreads();
  // LN: 16 threads per row, 16 cols each
  int row = tid >> 4, sub = tid & 15;
  int m = m0 + row;
  float x[16];
  float sum = 0.f, sumsq = 0.f;
#pragma unroll
  for (int i = 0; i < 4; i++) {
    int col = sub * 16 + i * 4;
    float4 xv = *reinterpret_cast<const float4*>(X + m * SD + col);
    float4 bb = *reinterpret_cast<const float4*>(bfv + col);
    x[i * 4 + 0] = Cl[row][col + 0] + xv.x + bb.x;
    x[i * 4 + 1] = Cl[row][col + 1] + xv.y + bb.y;
    x[i * 4 + 2] = Cl[row][col + 2] + xv.z + bb.z;
    x[i * 4 + 3] = Cl[row][col + 3] + xv.w + bb.w;
  }
#pragma unroll
  for (int c = 0; c < 16; c++) { sum += x[c]; sumsq += x[c] * x[c]; }
  sum += __shfl_xor(sum, 1);  sumsq += __shfl_xor(sumsq, 1);
  sum += __shfl_xor(sum, 2);  sumsq += __shfl_xor(sumsq, 2);
  sum += __shfl_xor(sum, 4);  sumsq += __shfl_xor(sumsq, 4);
  sum += __shfl_xor(sum, 8);  sumsq += __shfl_xor(sumsq, 8);
  float mean = sum * (1.0f / 256.0f);
  float var = sumsq * (1.0f / 256.0f) - mean * mean;
  float rstd = rsqrtf(var + 1e-6f);
#pragma unroll
  for (int i = 0; i < 4; i++) {
    int col = sub * 16 + i * 4;
    float4 gv = *reinterpret_cast<const float4*>(gamma + col);
    float4 bv2 = *reinterpret_cast<const float4*>(beta + col);
    float4 ov;
    ov.x = (x[i * 4 + 0] - mean) * rstd * gv.x + bv2.x;
    ov.y = (x[i * 4 + 1] - mean) * rstd * gv.y + bv2.y;
    ov.z = (x[i * 4 + 2] - mean) * rstd * gv.z + bv2.z;
    ov.w = (x[i * 4 + 3] - mean) * rstd * gv.w + bv2.w;
    *reinterpret_cast<float4*>(out + m * SD + col) = ov;
  }
}

extern "C" void kernel_launch(void* const* d_in, const int* in_sizes, int n_in,
                              void* d_out, int out_size, void* d_ws, size_t ws_size,
                              hipStream_t stream) {
  const float* X  = (const float*)d_in[0];
  const float* Wq = (const float*)d_in[1];
  const float* Wk = (const float*)d_in[2];
  const float* Wv = (const float*)d_in[3];
  const float* Wf = (const float*)d_in[4];
  const float* bf = (const float*)d_in[5];
  const float* gm = (const float*)d_in[6];
  const float* bt = (const float*)d_in[7];
  float* out = (float*)d_out;
  unsigned short* ws = (unsigned short*)d_ws;

  qkv_k<<<dim3(128, 6), 256, 0, stream>>>(X, Wq, Wk, Wv, Wf, ws);
  attn_k<<<dim3(512), 512, 0, stream>>>(ws, ws);
  final_k<<<512, 256, 0, stream>>>(ws, X, bf, gm, bt, out);
}